// Round 4
// baseline (158458.313 us; speedup 1.0000x reference)
//
#include <hip/hip_runtime.h>
#include <hip/hip_bf16.h>

#define T_STEPS 16384
#define COMD 128
#define INPD 512
#define HIDD 2048
#define OUTD 512
#define DIN 640
#define SCALE_F 35.0f
#define NA 16      // WGs per agent
#define HSA 128    // hidden rows per WG

using u16 = unsigned short;
using u32 = unsigned int;

__device__ __forceinline__ float lrelu(float x){ return x >= 0.f ? x : 0.01f*x; }
__device__ __forceinline__ float bf2f(u16 u){ return __uint_as_float(((u32)u)<<16); }
__device__ __forceinline__ u16 f2bf(float f){ u32 x = __float_as_uint(f); return (u16)((x + 0x7fffu + ((x>>16)&1u)) >> 16); }
__device__ __forceinline__ u32 aload(const u32* p){ return __hip_atomic_load(p, __ATOMIC_RELAXED, __HIP_MEMORY_SCOPE_AGENT); }
__device__ __forceinline__ void astore(u32* p, u32 v){ __hip_atomic_store(p, v, __ATOMIC_RELAXED, __HIP_MEMORY_SCOPE_AGENT); }
__device__ __forceinline__ u32 tagf(float f, u32 tg){ return (__float_as_uint(f) & ~3u) | tg; }

// ---------------- prep: base1/base2 = W1[:, :512] @ i + b ----------------
__global__ void __launch_bounds__(256) prep_base_kernel(
    const float* __restrict__ I1, const float* __restrict__ I2,
    const float* __restrict__ W11, const float* __restrict__ b11,
    const float* __restrict__ W21, const float* __restrict__ b21,
    float* __restrict__ base)
{
  int row = blockIdx.x*4 + (threadIdx.x>>6);   // 0..4095
  int lane = threadIdx.x & 63;
  int agent = row >> 11;
  int h = row & 2047;
  const float* W  = agent ? W21 : W11;
  const float* in = agent ? I2  : I1;   // row 0 only
  const float* bv = agent ? b21 : b11;
  float acc = 0.f;
  #pragma unroll
  for (int k = 0; k < 8; ++k)
    acc += W[(size_t)h*DIN + k*64 + lane] * in[k*64 + lane];
  #pragma unroll
  for (int off = 32; off; off >>= 1) acc += __shfl_xor(acc, off);
  if (lane == 0) base[agent*HIDD + h] = acc + bv[h];
}

// ---------------- prep: bf16 out-head weights (rows 0..511) ----------------
__global__ void __launch_bounds__(256) cvt_kernel(
    const float* __restrict__ W12, const float* __restrict__ W22,
    u16* __restrict__ o1, u16* __restrict__ o2)
{
  size_t i = ((size_t)blockIdx.x*256 + threadIdx.x)*4;   // < 512*2048
  float4 a = *reinterpret_cast<const float4*>(W12 + i);
  float4 b = *reinterpret_cast<const float4*>(W22 + i);
  ushort4 ua = { f2bf(a.x), f2bf(a.y), f2bf(a.z), f2bf(a.w) };
  ushort4 ub = { f2bf(b.x), f2bf(b.y), f2bf(b.z), f2bf(b.w) };
  *reinterpret_cast<ushort4*>(o1 + i) = ua;
  *reinterpret_cast<ushort4*>(o2 + i) = ub;
}

// ---------------- agent-split recurrence, 1 wave per WG ----------------
// WGs 0..15 = agent1 (128 hidden rows each), 16..31 = agent2.
// Handoff: producer WG g writes its 128 fp32 partial logits with the step
// tag (t+1)&3 embedded in the low 2 mantissa bits; consumers poll/gather in
// ONE round-trip (per-word tags, no flags, no fences needed).
// Overwrite safety: A1 produces P1(t+1) only after consuming P2(t), which
// every A2 WG published only after fully reading P1(t); symmetric for P2.
// 0xAA ws poison has tag 2; iter-0 target tag is 1, and every word is
// rewritten every iteration, so poison is never consumed.
__global__ void __launch_bounds__(64, 1) team_kernel(
    const float* __restrict__ W11, const float* __restrict__ W21,
    const float* __restrict__ W12, const float* __restrict__ W22,
    const float* __restrict__ b12, const float* __restrict__ b22,
    const float* __restrict__ base,
    u32* __restrict__ P1, u32* __restrict__ P2,
    void* __restrict__ hist1, void* __restrict__ hist2, int hf32)
{
  __shared__ float sWa[HSA*129];   // W1[:,512:] slice [h][c], pad129 (conflict-free)
  __shared__ float sU[COMD*129];   // W2[512:,:] slice [o][h], pad129
  __shared__ float s_h[HSA];
  __shared__ float s_com[COMD];

  const int wg = blockIdx.x;
  const bool isA1 = (wg < NA);
  const int g = isA1 ? wg : wg - NA;
  const int h0 = g * HSA;
  const int l = threadIdx.x;       // 0..63, single wave

  const float* W1 = isA1 ? W11 : W21;
  const float* W2 = isA1 ? W12 : W22;
  const float* bOth = isA1 ? b22 : b12;  // bias of the PRODUCING agent's layer-2
  u32* Pout = isA1 ? P1 : P2;
  u32* Pin  = isA1 ? P2 : P1;
  void* hist = isA1 ? hist1 : hist2;
  float* histf = (float*)hist; u16* histu = (u16*)hist;

  for (int idx = l; idx < HSA*COMD; idx += 64) {
    int r = idx >> 7, c = idx & 127;
    sWa[r*129+c] = W1[(size_t)(h0+r)*DIN + INPD + c];
    sU [r*129+c] = W2[(size_t)(OUTD+r)*HIDD + h0 + c];
  }
  const float bc0 = bOth[OUTD + l];
  const float bc1 = bOth[OUTD + 64 + l];
  const float sb0 = base[(isA1?0:HIDD) + h0 + l];
  const float sb1 = base[(isA1?0:HIDD) + h0 + 64 + l];
  float st0 = 0.f, st1 = 0.f;
  __syncthreads();

  for (int t = 0; t < T_STEPS; ++t) {
    const float invd = 1.f / (float)(t+1);
    const u32 tg = (u32)((t+1) & 3);

    // ================= produce (A1 first; A2 after consume) =================
    auto produce = [&]() {
      float x0 = lrelu(sb0 + st0*invd);
      float x1 = lrelu(sb1 + st1*invd);
      s_h[l] = x0; s_h[64+l] = x1;
      __syncthreads();
      float p0 = 0.f, p1 = 0.f;
      #pragma unroll 16
      for (int h = 0; h < HSA; ++h) {
        float hv = s_h[h];
        p0 += sU[l*129+h]*hv;
        p1 += sU[(64+l)*129+h]*hv;
      }
      astore(&Pout[g*COMD + l],      tagf(p0, tg));
      astore(&Pout[g*COMD + 64 + l], tagf(p1, tg));
    };

    if (isA1) produce();

    // ================= consume =================
    {
      u32 v0[NA], v1[NA];
      for (;;) {
        #pragma unroll
        for (int j = 0; j < NA; ++j) v0[j] = aload(&Pin[j*COMD + l]);
        #pragma unroll
        for (int j = 0; j < NA; ++j) v1[j] = aload(&Pin[j*COMD + 64 + l]);
        u32 bad = 0;
        #pragma unroll
        for (int j = 0; j < NA; ++j)
          bad |= ((v0[j]&3u)^tg) | ((v1[j]&3u)^tg);
        if (!bad) break;
        __builtin_amdgcn_s_sleep(1);
      }
      float z0 = bc0, z1 = bc1;
      #pragma unroll
      for (int j = 0; j < NA; ++j) {
        z0 += __uint_as_float(v0[j] & ~3u);
        z1 += __uint_as_float(v1[j] & ~3u);
      }
      z0 = SCALE_F * lrelu(z0);
      z1 = SCALE_F * lrelu(z1);
      float m = fmaxf(z0, z1);
      #pragma unroll
      for (int off = 32; off; off >>= 1) m = fmaxf(m, __shfl_xor(m, off));
      float e0 = __expf(z0 - m), e1 = __expf(z1 - m);
      float s = e0 + e1;
      #pragma unroll
      for (int off = 32; off; off >>= 1) s += __shfl_xor(s, off);
      float rs = 1.f / s;
      s_com[l] = e0 * rs; s_com[64+l] = e1 * rs;
      __syncthreads();
      float a0 = 0.f, a1 = 0.f;
      #pragma unroll 16
      for (int c = 0; c < COMD; ++c) {
        float cv = s_com[c];
        a0 += sWa[l*129+c]*cv;
        a1 += sWa[(64+l)*129+c]*cv;
      }
      st0 += a0; st1 += a1;
      float x0 = lrelu(sb0 + st0*invd);
      float x1 = lrelu(sb1 + st1*invd);
      if (hf32) {
        histf[(size_t)t*HIDD + h0 + l]      = x0;
        histf[(size_t)t*HIDD + h0 + 64 + l] = x1;
      } else {
        histu[(size_t)t*HIDD + h0 + l]      = f2bf(x0);
        histu[(size_t)t*HIDD + h0 + 64 + l] = f2bf(x1);
      }
    }

    if (!isA1) produce();   // A2: h recomputed from same st/invd == h2
  }
}

// ---------------- dense out-heads from hidden history (t-blocked x8) ----------------
__global__ void __launch_bounds__(256) out_kernel(
    const void* __restrict__ hist1, const void* __restrict__ hist2,
    const u16* __restrict__ Wb1, const u16* __restrict__ Wb2,
    const float* __restrict__ b12, const float* __restrict__ b22,
    float* __restrict__ out, int hf32)
{
  __shared__ float hl[8][2048];
  const int head = blockIdx.x & 1;
  const int t0 = (blockIdx.x >> 1) * 8;
  const int tid = threadIdx.x;
  const void* hist = head ? hist2 : hist1;
  const u16* W = head ? Wb2 : Wb1;
  const float* bias = head ? b22 : b12;
  float* op = out + (size_t)head * T_STEPS * OUTD;

  if (hf32) {
    const float* hf = (const float*)hist;
    for (int idx = tid; idx < 8*2048; idx += 256)
      hl[idx>>11][idx&2047] = hf[(size_t)t0*HIDD + idx];
  } else {
    const u16* hu = (const u16*)hist;
    for (int idx = tid; idx < 8*2048; idx += 256)
      hl[idx>>11][idx&2047] = bf2f(hu[(size_t)t0*HIDD + idx]);
  }
  __syncthreads();

  const int wave = tid >> 6, lane = tid & 63;
  for (int row = wave; row < OUTD; row += 4) {
    const u16* wr = W + (size_t)row*HIDD;
    float acc[8] = {0,0,0,0,0,0,0,0};
    #pragma unroll
    for (int k = 0; k < 8; ++k) {
      const int e = k*256 + lane*4;
      uint2 pw = *reinterpret_cast<const uint2*>(wr + e);
      float w0 = bf2f((u16)(pw.x & 0xffffu));
      float w1 = bf2f((u16)(pw.x >> 16));
      float w2 = bf2f((u16)(pw.y & 0xffffu));
      float w3 = bf2f((u16)(pw.y >> 16));
      #pragma unroll
      for (int tt = 0; tt < 8; ++tt) {
        const float4 hv = *reinterpret_cast<const float4*>(&hl[tt][e]);
        acc[tt] += w0*hv.x + w1*hv.y + w2*hv.z + w3*hv.w;
      }
    }
    #pragma unroll
    for (int tt = 0; tt < 8; ++tt) {
      float a = acc[tt];
      #pragma unroll
      for (int off = 32; off; off >>= 1) a += __shfl_xor(a, off);
      acc[tt] = a;
    }
    if (lane == 0) {
      const float b = bias[row];
      #pragma unroll
      for (int tt = 0; tt < 8; ++tt)
        op[(size_t)(t0+tt)*OUTD + row] = lrelu(acc[tt] + b);
    }
  }
}

extern "C" void kernel_launch(void* const* d_in, const int* in_sizes, int n_in,
                              void* d_out, int out_size, void* d_ws, size_t ws_size,
                              hipStream_t stream)
{
  const float* I1  = (const float*)d_in[0];
  const float* I2  = (const float*)d_in[1];
  const float* W11 = (const float*)d_in[2];
  const float* b11 = (const float*)d_in[3];
  const float* W12 = (const float*)d_in[4];
  const float* b12 = (const float*)d_in[5];
  const float* W21 = (const float*)d_in[6];
  const float* b21 = (const float*)d_in[7];
  const float* W22 = (const float*)d_in[8];
  const float* b22 = (const float*)d_in[9];

  char* ws = (char*)d_ws;
  float* base = (float*)ws;                 // 2*2048 f32
  u32* P1 = (u32*)(ws + 16384);             // 16*128 u32 (tagged fp32)
  u32* P2 = (u32*)(ws + 24576);             // 16*128 u32
  char* hist1 = ws + 65536;
  const size_t histF = (size_t)T_STEPS*HIDD*4;
  const size_t histU = (size_t)T_STEPS*HIDD*2;
  const size_t wbB   = (size_t)OUTD*HIDD*2;
  const size_t needF = 65536 + 2*histF + 2*wbB;
  int hf32 = (ws_size >= needF) ? 1 : 0;
  const size_t hb = hf32 ? histF : histU;
  char* hist2 = hist1 + hb;
  u16* Wb1 = (u16*)(hist2 + hb);
  u16* Wb2 = Wb1 + (size_t)OUTD*HIDD;

  hipMemsetAsync(ws + 16384, 0, 16384, stream);   // P1+P2 -> tag 0
  prep_base_kernel<<<1024, 256, 0, stream>>>(I1, I2, W11, b11, W21, b21, base);
  cvt_kernel<<<1024, 256, 0, stream>>>(W12, W22, Wb1, Wb2);

  void* h1v = (void*)hist1; void* h2v = (void*)hist2;
  void* kargs[] = { (void*)&W11, (void*)&W21, (void*)&W12, (void*)&W22,
                    (void*)&b12, (void*)&b22, (void*)&base,
                    (void*)&P1, (void*)&P2,
                    (void*)&h1v, (void*)&h2v, (void*)&hf32 };
  hipLaunchCooperativeKernel((const void*)team_kernel, dim3(2*NA), dim3(64),
                             kargs, 0, stream);

  out_kernel<<<(T_STEPS/8)*2, 256, 0, stream>>>(h1v, h2v, Wb1, Wb2, b12, b22,
                                                (float*)d_out, hf32);
}

// Round 5
// 133782.825 us; speedup vs baseline: 1.1844x; 1.1844x over previous
//
#include <hip/hip_runtime.h>
#include <hip/hip_bf16.h>

#define T_STEPS 16384
#define COMD 128
#define INPD 512
#define HIDD 2048
#define OUTD 512
#define DIN 640
#define SCALE_F 35.0f
#define NA 16      // WGs per agent
#define HSA 128    // hidden rows per WG

using u16 = unsigned short;
using u32 = unsigned int;
using u64 = unsigned long long;

__device__ __forceinline__ float lrelu(float x){ return x >= 0.f ? x : 0.01f*x; }
__device__ __forceinline__ float bf2f(u16 u){ return __uint_as_float(((u32)u)<<16); }
__device__ __forceinline__ u16 f2bf(float f){ u32 x = __float_as_uint(f); return (u16)((x + 0x7fffu + ((x>>16)&1u)) >> 16); }
__device__ __forceinline__ u64 aload64(const u64* p){ return __hip_atomic_load(p, __ATOMIC_RELAXED, __HIP_MEMORY_SCOPE_AGENT); }
__device__ __forceinline__ void astore64(u64* p, u64 v){ __hip_atomic_store(p, v, __ATOMIC_RELAXED, __HIP_MEMORY_SCOPE_AGENT); }
__device__ __forceinline__ u32 tagf(float f, u32 tg){ return (__float_as_uint(f) & ~3u) | tg; }

// ---------------- prep: base1/base2 = W1[:, :512] @ i + b ----------------
__global__ void __launch_bounds__(256) prep_base_kernel(
    const float* __restrict__ I1, const float* __restrict__ I2,
    const float* __restrict__ W11, const float* __restrict__ b11,
    const float* __restrict__ W21, const float* __restrict__ b21,
    float* __restrict__ base)
{
  int row = blockIdx.x*4 + (threadIdx.x>>6);   // 0..4095
  int lane = threadIdx.x & 63;
  int agent = row >> 11;
  int h = row & 2047;
  const float* W  = agent ? W21 : W11;
  const float* in = agent ? I2  : I1;   // row 0 only
  const float* bv = agent ? b21 : b11;
  float acc = 0.f;
  #pragma unroll
  for (int k = 0; k < 8; ++k)
    acc += W[(size_t)h*DIN + k*64 + lane] * in[k*64 + lane];
  #pragma unroll
  for (int off = 32; off; off >>= 1) acc += __shfl_xor(acc, off);
  if (lane == 0) base[agent*HIDD + h] = acc + bv[h];
}

// ---------------- prep: bf16 out-head weights (rows 0..511) ----------------
__global__ void __launch_bounds__(256) cvt_kernel(
    const float* __restrict__ W12, const float* __restrict__ W22,
    u16* __restrict__ o1, u16* __restrict__ o2)
{
  size_t i = ((size_t)blockIdx.x*256 + threadIdx.x)*4;   // < 512*2048
  float4 a = *reinterpret_cast<const float4*>(W12 + i);
  float4 b = *reinterpret_cast<const float4*>(W22 + i);
  ushort4 ua = { f2bf(a.x), f2bf(a.y), f2bf(a.z), f2bf(a.w) };
  ushort4 ub = { f2bf(b.x), f2bf(b.y), f2bf(b.z), f2bf(b.w) };
  *reinterpret_cast<ushort4*>(o1 + i) = ua;
  *reinterpret_cast<ushort4*>(o2 + i) = ub;
}

// ---------------- agent-split recurrence, 2 waves (128 thr) per WG ----------------
// WGs 0..15 = agent1 (128 hidden rows each), 16..31 = agent2.
// Handoff: tag-in-payload. Producer packs logit pair (2k,2k+1) with step tag
// (t+1)&3 in the low 2 mantissa bits of each fp32, one 8B atomic store.
// Consumers poll+gather in ONE visibility round-trip (per-word tags; no
// flags, no fences, relaxed atomics only). Each wave gathers redundantly so
// the retry loop needs no cross-wave coordination; softmax and the com
// broadcast are pure in-register wave shuffles (com[c] = lane c>>1, slot c&1).
// Overwrite safety: WG X overwrites its P-block / s_h only after consuming
// the other agent's step-t data, which was published only after every WG of
// the other agent fully read X's step-t data. One __syncthreads per step.
// 0xAA poison tag=2, memset tag=0; step-0 tag=1 -> poison never consumed.
__global__ void __launch_bounds__(128, 1) team_kernel(
    const float* __restrict__ W11, const float* __restrict__ W21,
    const float* __restrict__ W12, const float* __restrict__ W22,
    const float* __restrict__ b12, const float* __restrict__ b22,
    const float* __restrict__ base,
    u64* __restrict__ P1, u64* __restrict__ P2,
    void* __restrict__ hist1, void* __restrict__ hist2, int hf32)
{
  __shared__ float4 sWa4[HSA*32];   // W1[:,512:] slice, [r][c4 ^ (r&7)] swizzled
  __shared__ float4 sU4[COMD*32];   // W2[512:,:] slice, [o][h4 ^ (o&7)] swizzled
  __shared__ float s_h[HSA];

  const int wg = blockIdx.x;
  const bool isA1 = (wg < NA);
  const int g = isA1 ? wg : wg - NA;
  const int h0 = g * HSA;
  const int tid = threadIdx.x;     // 0..127
  const int l = tid & 63;

  const float* W1 = isA1 ? W11 : W21;
  const float* W2 = isA1 ? W12 : W22;
  const float* bOth = isA1 ? b22 : b12;  // layer-2 bias of the agent we CONSUME from
  u64* Pout = isA1 ? P1 : P2;
  u64* Pin  = isA1 ? P2 : P1;
  void* hist = isA1 ? hist1 : hist2;
  float* histf = (float*)hist; u16* histu = (u16*)hist;

  for (int idx = tid; idx < HSA*32; idx += 128) {
    int r = idx >> 5, c = idx & 31;
    sWa4[r*32 + (c ^ (r&7))] =
      *reinterpret_cast<const float4*>(W1 + (size_t)(h0+r)*DIN + INPD + 4*c);
    sU4[r*32 + (c ^ (r&7))] =
      *reinterpret_cast<const float4*>(W2 + (size_t)(OUTD+r)*HIDD + h0 + 4*c);
  }
  const float bc0 = bOth[OUTD + 2*l];
  const float bc1 = bOth[OUTD + 2*l + 1];
  const float sb  = base[(isA1?0:HIDD) + h0 + tid];
  float st = 0.f;
  __syncthreads();

  const float4* hp4 = (const float4*)s_h;

  for (int t = 0; t < T_STEPS; ++t) {
    const float invd = 1.f / (float)(t+1);
    const u32 tg = (u32)((t+1) & 3);

    if (isA1) {
      // ---- produce L1(t): h1a from current w-state, publish U1-slice @ h1a ----
      s_h[tid] = lrelu(sb + st*invd);
      __syncthreads();
      float p = 0.f;
      #pragma unroll
      for (int c = 0; c < 32; ++c) {
        float4 w4 = sU4[tid*32 + (c ^ (tid&7))];
        float4 h4 = hp4[c];                      // broadcast read
        p += w4.x*h4.x + w4.y*h4.y + w4.z*h4.z + w4.w*h4.w;
      }
      float phi = __shfl_down(p, 1);
      if (!(tid & 1))
        astore64(&Pout[g*64 + (tid>>1)],
                 ((u64)tagf(phi, tg) << 32) | (u64)tagf(p, tg));
    }

    // ---- consume (A2 consumes L1; A1 consumes L2). Redundant per wave. ----
    u64 v[NA];
    for (;;) {
      #pragma unroll
      for (int j = 0; j < NA; ++j) v[j] = aload64(&Pin[j*64 + l]);
      u32 bad = 0;
      #pragma unroll
      for (int j = 0; j < NA; ++j)
        bad |= (((u32)v[j] & 3u) ^ tg) | (((u32)(v[j] >> 32) & 3u) ^ tg);
      if (!bad) break;
      __builtin_amdgcn_s_sleep(1);
    }
    float z0 = bc0, z1 = bc1;
    #pragma unroll
    for (int j = 0; j < NA; ++j) {
      z0 += __uint_as_float((u32)v[j] & ~3u);
      z1 += __uint_as_float((u32)(v[j] >> 32) & ~3u);
    }
    z0 = SCALE_F * lrelu(z0);
    z1 = SCALE_F * lrelu(z1);
    float m = fmaxf(z0, z1);
    #pragma unroll
    for (int off = 32; off; off >>= 1) m = fmaxf(m, __shfl_xor(m, off));
    float e0 = __expf(z0 - m), e1 = __expf(z1 - m);
    float s = e0 + e1;
    #pragma unroll
    for (int off = 32; off; off >>= 1) s += __shfl_xor(s, off);
    float rs = 1.f / s;
    float c0 = e0 * rs, c1 = e1 * rs;   // com[2l], com[2l+1]

    // state += Wa_slice @ com   (com via wave shuffles; swizzled b128 reads)
    float a = 0.f;
    #pragma unroll
    for (int cg = 0; cg < 32; ++cg) {
      float4 w4 = sWa4[tid*32 + (cg ^ (tid&7))];
      a += w4.x*__shfl(c0, 2*cg)   + w4.y*__shfl(c1, 2*cg)
         + w4.z*__shfl(c0, 2*cg+1) + w4.w*__shfl(c1, 2*cg+1);
    }
    st += a;
    float x = lrelu(sb + st*invd);
    if (hf32) histf[(size_t)t*HIDD + h0 + tid] = x;
    else      histu[(size_t)t*HIDD + h0 + tid] = f2bf(x);

    if (!isA1) {
      // ---- produce L2(t): publish U2-slice @ h2 (h2 == x just computed) ----
      s_h[tid] = x;
      __syncthreads();
      float p = 0.f;
      #pragma unroll
      for (int c = 0; c < 32; ++c) {
        float4 w4 = sU4[tid*32 + (c ^ (tid&7))];
        float4 h4 = hp4[c];
        p += w4.x*h4.x + w4.y*h4.y + w4.z*h4.z + w4.w*h4.w;
      }
      float phi = __shfl_down(p, 1);
      if (!(tid & 1))
        astore64(&Pout[g*64 + (tid>>1)],
                 ((u64)tagf(phi, tg) << 32) | (u64)tagf(p, tg));
    }
  }
}

// ---------------- dense out-heads from hidden history (t-blocked x8) ----------------
__global__ void __launch_bounds__(256) out_kernel(
    const void* __restrict__ hist1, const void* __restrict__ hist2,
    const u16* __restrict__ Wb1, const u16* __restrict__ Wb2,
    const float* __restrict__ b12, const float* __restrict__ b22,
    float* __restrict__ out, int hf32)
{
  __shared__ float hl[8][2048];
  const int head = blockIdx.x & 1;
  const int t0 = (blockIdx.x >> 1) * 8;
  const int tid = threadIdx.x;
  const void* hist = head ? hist2 : hist1;
  const u16* W = head ? Wb2 : Wb1;
  const float* bias = head ? b22 : b12;
  float* op = out + (size_t)head * T_STEPS * OUTD;

  if (hf32) {
    const float* hf = (const float*)hist;
    for (int idx = tid; idx < 8*2048; idx += 256)
      hl[idx>>11][idx&2047] = hf[(size_t)t0*HIDD + idx];
  } else {
    const u16* hu = (const u16*)hist;
    for (int idx = tid; idx < 8*2048; idx += 256)
      hl[idx>>11][idx&2047] = bf2f(hu[(size_t)t0*HIDD + idx]);
  }
  __syncthreads();

  const int wave = tid >> 6, lane = tid & 63;
  for (int row = wave; row < OUTD; row += 4) {
    const u16* wr = W + (size_t)row*HIDD;
    float acc[8] = {0,0,0,0,0,0,0,0};
    #pragma unroll
    for (int k = 0; k < 8; ++k) {
      const int e = k*256 + lane*4;
      uint2 pw = *reinterpret_cast<const uint2*>(wr + e);
      float w0 = bf2f((u16)(pw.x & 0xffffu));
      float w1 = bf2f((u16)(pw.x >> 16));
      float w2 = bf2f((u16)(pw.y & 0xffffu));
      float w3 = bf2f((u16)(pw.y >> 16));
      #pragma unroll
      for (int tt = 0; tt < 8; ++tt) {
        const float4 hv = *reinterpret_cast<const float4*>(&hl[tt][e]);
        acc[tt] += w0*hv.x + w1*hv.y + w2*hv.z + w3*hv.w;
      }
    }
    #pragma unroll
    for (int tt = 0; tt < 8; ++tt) {
      float a = acc[tt];
      #pragma unroll
      for (int off = 32; off; off >>= 1) a += __shfl_xor(a, off);
      acc[tt] = a;
    }
    if (lane == 0) {
      const float b = bias[row];
      #pragma unroll
      for (int tt = 0; tt < 8; ++tt)
        op[(size_t)(t0+tt)*OUTD + row] = lrelu(acc[tt] + b);
    }
  }
}

extern "C" void kernel_launch(void* const* d_in, const int* in_sizes, int n_in,
                              void* d_out, int out_size, void* d_ws, size_t ws_size,
                              hipStream_t stream)
{
  const float* I1  = (const float*)d_in[0];
  const float* I2  = (const float*)d_in[1];
  const float* W11 = (const float*)d_in[2];
  const float* b11 = (const float*)d_in[3];
  const float* W12 = (const float*)d_in[4];
  const float* b12 = (const float*)d_in[5];
  const float* W21 = (const float*)d_in[6];
  const float* b21 = (const float*)d_in[7];
  const float* W22 = (const float*)d_in[8];
  const float* b22 = (const float*)d_in[9];

  char* ws = (char*)d_ws;
  float* base = (float*)ws;                 // 2*2048 f32
  u64* P1 = (u64*)(ws + 16384);             // 16*64 u64 (tagged fp32 pairs)
  u64* P2 = (u64*)(ws + 24576);
  char* hist1 = ws + 65536;
  const size_t histF = (size_t)T_STEPS*HIDD*4;
  const size_t histU = (size_t)T_STEPS*HIDD*2;
  const size_t wbB   = (size_t)OUTD*HIDD*2;
  const size_t needF = 65536 + 2*histF + 2*wbB;
  int hf32 = (ws_size >= needF) ? 1 : 0;
  const size_t hb = hf32 ? histF : histU;
  char* hist2 = hist1 + hb;
  u16* Wb1 = (u16*)(hist2 + hb);
  u16* Wb2 = Wb1 + (size_t)OUTD*HIDD;

  hipMemsetAsync(ws + 16384, 0, 16384, stream);   // P1+P2 -> tag 0
  prep_base_kernel<<<1024, 256, 0, stream>>>(I1, I2, W11, b11, W21, b21, base);
  cvt_kernel<<<1024, 256, 0, stream>>>(W12, W22, Wb1, Wb2);

  void* h1v = (void*)hist1; void* h2v = (void*)hist2;
  void* kargs[] = { (void*)&W11, (void*)&W21, (void*)&W12, (void*)&W22,
                    (void*)&b12, (void*)&b22, (void*)&base,
                    (void*)&P1, (void*)&P2,
                    (void*)&h1v, (void*)&h2v, (void*)&hf32 };
  hipLaunchCooperativeKernel((const void*)team_kernel, dim3(2*NA), dim3(128),
                             kargs, 0, stream);

  out_kernel<<<(T_STEPS/8)*2, 256, 0, stream>>>(h1v, h2v, Wb1, Wb2, b12, b22,
                                                (float*)d_out, hf32);
}